// Round 4
// baseline (915.367 us; speedup 1.0000x reference)
//
#include <hip/hip_runtime.h>

typedef __bf16 bf16x8 __attribute__((ext_vector_type(8)));
typedef __bf16 bf16x4 __attribute__((ext_vector_type(4)));
typedef float  floatx4 __attribute__((ext_vector_type(4)));

#define Vv 25
#define Tt 14
#define Ee 64
#define Hh 128
#define Ll 32
#define Ccc 8
#define G3 384
#define TABP 396   // token-table row stride (bf16): word-stride 198 = 6 mod 32
#define HP   136   // h row stride (bf16): 128+8, rows 16B-aligned
#define CXP  72    // ctx row stride (bf16): 64+8

// ---------------------------------------------------------------------------
// Kernel A: token -> input-projection tables (f32, in ws), biases folded:
//   enc_tab[v][j] = emb_enc[v]·W_ih_e[j] + b_ih_e[j] + (j<256 ? b_hh_e[j] : 0)
//   dec_tab[v][j] = emb_dec[v]·W_ih_d[j][:64] + b_ih_d[j] + (j<256 ? b_hh_d[j] : 0)
// (n-gate keeps b_hh separate: n = tanh(i_n + r*(h_n + b_hh_n)))
// ---------------------------------------------------------------------------
extern "C" __global__ void __launch_bounds__(256)
cvae_tables(const float* __restrict__ emb_enc, const float* __restrict__ W_ih_e,
            const float* __restrict__ b_ih_e, const float* __restrict__ b_hh_e,
            const float* __restrict__ emb_dec, const float* __restrict__ W_ih_d,
            const float* __restrict__ b_ih_d, const float* __restrict__ b_hh_d,
            float* __restrict__ ws)
{
    int id = blockIdx.x * 256 + threadIdx.x;
    if (id >= 2 * Vv * G3) return;
    int half = id / (Vv * G3);
    int r = id % (Vv * G3);
    int v = r / G3, j = r % G3;
    if (half == 0) {
        float acc = b_ih_e[j] + ((j < 2 * Hh) ? b_hh_e[j] : 0.0f);
        const float* e = emb_enc + v * Ee;
        const float* w = W_ih_e + j * Ee;
        #pragma unroll 4
        for (int k = 0; k < Ee; k++) acc += e[k] * w[k];
        ws[v * G3 + j] = acc;
    } else {
        float acc = b_ih_d[j] + ((j < 2 * Hh) ? b_hh_d[j] : 0.0f);
        const float* e = emb_dec + v * Ee;
        const float* w = W_ih_d + j * 104;
        #pragma unroll 4
        for (int k = 0; k < Ee; k++) acc += e[k] * w[k];
        ws[Vv * G3 + v * G3 + j] = acc;
    }
}

__device__ __forceinline__ float rcp_f(float x) { return __builtin_amdgcn_rcpf(x); }
__device__ __forceinline__ float sigm(float x)  { return rcp_f(1.0f + __expf(-x)); }
__device__ __forceinline__ float tanhg(float x) { return 1.0f - 2.0f * rcp_f(1.0f + __expf(2.0f * x)); }

// ---------------------------------------------------------------------------
// Fused CVAE forward. 512 thr = 8 waves, 64 batch rows/block.
// gh^T = W·h^T: A-frag = stationary W rows in regs; B-frag = h in LDS bf16;
// C tile: col=lane&15=batch, row=q*4+reg=j-local. Wave w owns j in [16w,16w+16).
// Double-buffered h: one barrier per GRU step. Vocab proj for step t-1 fused
// into iter t (reuses hf fragments). LDS = 64728 B.
// ---------------------------------------------------------------------------
extern "C" __global__ void __launch_bounds__(512)
cvae_mfma(const int* __restrict__ x, const float* __restrict__ cin,
          const float* __restrict__ eps,
          const float* __restrict__ W_hh_e, const float* __restrict__ b_hh_e,
          const float* __restrict__ W_mu, const float* __restrict__ b_mu,
          const float* __restrict__ W_lv, const float* __restrict__ b_lv,
          const float* __restrict__ W_fch, const float* __restrict__ b_fch,
          const float* __restrict__ W_ih_d, const float* __restrict__ W_hh_d,
          const float* __restrict__ b_hh_d,
          const float* __restrict__ W_out, const float* __restrict__ b_out,
          const float* __restrict__ tabs, float* __restrict__ out, int Btot)
{
    __shared__ __attribute__((aligned(16))) __bf16 hbuf[2][64 * HP];  // 34816 B
    __shared__ __attribute__((aligned(16))) __bf16 tab_s[Vv * TABP];  // 19800 B
    __shared__ __attribute__((aligned(16))) __bf16 ctx_s[64 * CXP];   //  9216 B
    __shared__ unsigned char x_s[64 * Tt];                            //   896 B

    const int tid  = threadIdx.x;
    const int w    = tid >> 6;
    const int lane = tid & 63;
    const int li   = lane & 15;
    const int q    = lane >> 4;
    const int b0   = blockIdx.x * 64;
    const size_t MU_OFF = (size_t)Btot * 13 * Vv;
    const size_t LV_OFF = MU_OFF + (size_t)Btot * Ll;
    const floatx4 zf = {0.f, 0.f, 0.f, 0.f};

    // ---- stage tokens + enc_tab (bf16), zero h buf0, stage c into ctx ----
    for (int i = tid; i < 64 * Tt; i += 512) x_s[i] = (unsigned char)x[(size_t)b0 * Tt + i];
    for (int i = tid; i < Vv * G3; i += 512)
        tab_s[(i / G3) * TABP + (i % G3)] = (__bf16)tabs[i];
    for (int i = tid; i < 64 * HP; i += 512) hbuf[0][i] = (__bf16)0.f;
    {   // c: tid = bb*8+cc covers 64x8 exactly
        int bb = tid >> 3, cc = tid & 7;
        ctx_s[bb * CXP + Ll + cc] = (__bf16)cin[((size_t)b0 + bb) * Ccc + cc];
    }
    {   // zero ctx cols 40..71 (K-padding for base MFMA)
        int bb = tid >> 3, k = tid & 7;
        #pragma unroll
        for (int kk = 0; kk < 4; kk++) ctx_s[bb * CXP + 40 + k * 4 + kk] = (__bf16)0.f;
    }

    // ---- encoder W_hh A-frags (stationary) + b_hh_n ----
    bf16x8 aW[3][4];
    #pragma unroll
    for (int role = 0; role < 3; role++)
        #pragma unroll
        for (int kb = 0; kb < 4; kb++) {
            const float* p = W_hh_e + (role * Hh + w * 16 + li) * Hh + kb * 32 + q * 8;
            bf16x8 f;
            #pragma unroll
            for (int jj = 0; jj < 8; jj++) f[jj] = (__bf16)p[jj];
            aW[role][kb] = f;
        }
    float bhn[4];
    #pragma unroll
    for (int r = 0; r < 4; r++) bhn[r] = b_hh_e[2 * Hh + w * 16 + q * 4 + r];

    float hreg[4][4];
    #pragma unroll
    for (int nt = 0; nt < 4; nt++)
        #pragma unroll
        for (int r = 0; r < 4; r++) hreg[nt][r] = 0.f;

    __syncthreads();

    // ---- one encoder GRU step: read hr, write hw, one barrier ----
    auto enc_step = [&](int t, const __bf16* hr, __bf16* hw) {
        bf16x8 hf[4][4];
        #pragma unroll
        for (int nt = 0; nt < 4; nt++)
            #pragma unroll
            for (int kb = 0; kb < 4; kb++)
                hf[nt][kb] = *(const bf16x8*)&hr[(nt * 16 + li) * HP + kb * 32 + q * 8];
        bf16x4 tR[4], tZ[4], tN[4];
        #pragma unroll
        for (int nt = 0; nt < 4; nt++) {
            int tok = x_s[(nt * 16 + li) * Tt + t];
            const __bf16* tp = &tab_s[tok * TABP + w * 16 + q * 4];
            tR[nt] = *(const bf16x4*)(tp);
            tZ[nt] = *(const bf16x4*)(tp + Hh);
            tN[nt] = *(const bf16x4*)(tp + 2 * Hh);
        }
        floatx4 acc[3][4];
        #pragma unroll
        for (int nt = 0; nt < 4; nt++)
            #pragma unroll
            for (int role = 0; role < 3; role++)
                acc[role][nt] = __builtin_amdgcn_mfma_f32_16x16x32_bf16(aW[role][0], hf[nt][0], zf, 0, 0, 0);
        #pragma unroll
        for (int kb = 1; kb < 4; kb++)
            #pragma unroll
            for (int role = 0; role < 3; role++)
                #pragma unroll
                for (int nt = 0; nt < 4; nt++)
                    acc[role][nt] = __builtin_amdgcn_mfma_f32_16x16x32_bf16(
                        aW[role][kb], hf[nt][kb], acc[role][nt], 0, 0, 0);
        #pragma unroll
        for (int nt = 0; nt < 4; nt++) {
            bf16x4 hv;
            #pragma unroll
            for (int r = 0; r < 4; r++) {
                float rr = sigm(acc[0][nt][r] + (float)tR[nt][r]);
                float zz = sigm(acc[1][nt][r] + (float)tZ[nt][r]);
                float nn = tanhg((float)tN[nt][r] + rr * (acc[2][nt][r] + bhn[r]));
                float h  = (1.f - zz) * nn + zz * hreg[nt][r];
                hreg[nt][r] = h;
                hv[r] = (__bf16)h;
            }
            *(bf16x4*)&hw[(nt * 16 + li) * HP + w * 16 + q * 4] = hv;
        }
        __syncthreads();
    };

    // ================= encoder: 14 steps (h_enc lands in hbuf[0]) ==========
    for (int t2 = 0; t2 < Tt; t2 += 2) {
        enc_step(t2,     hbuf[0], hbuf[1]);
        enc_step(t2 + 1, hbuf[1], hbuf[0]);
    }

    // ================= latent: mu / logvar / z =================
    {
        int b = tid & 63, g = w;
        size_t bg = (size_t)b0 + b;
        float cv[8];
        #pragma unroll
        for (int cc = 0; cc < 8; cc++) cv[cc] = cin[bg * Ccc + cc];

        float sm[4], sv[4];
        #pragma unroll
        for (int ii = 0; ii < 4; ii++) { sm[ii] = b_mu[g * 4 + ii]; sv[ii] = b_lv[g * 4 + ii]; }
        const __bf16* hp = &hbuf[0][b * HP];
        #pragma unroll 4
        for (int kb = 0; kb < 16; kb++) {
            bf16x8 h8 = *(const bf16x8*)&hp[kb * 8];
            #pragma unroll
            for (int jj = 0; jj < 8; jj++) {
                float hv = (float)h8[jj];
                int k = kb * 8 + jj;
                #pragma unroll
                for (int ii = 0; ii < 4; ii++) {
                    sm[ii] += hv * W_mu[(g * 4 + ii) * 136 + k];
                    sv[ii] += hv * W_lv[(g * 4 + ii) * 136 + k];
                }
            }
        }
        #pragma unroll
        for (int cc = 0; cc < 8; cc++)
            #pragma unroll
            for (int ii = 0; ii < 4; ii++) {
                sm[ii] += cv[cc] * W_mu[(g * 4 + ii) * 136 + Hh + cc];
                sv[ii] += cv[cc] * W_lv[(g * 4 + ii) * 136 + Hh + cc];
            }
        floatx4 smv, svv;
        #pragma unroll
        for (int ii = 0; ii < 4; ii++) { smv[ii] = sm[ii]; svv[ii] = sv[ii]; }
        *(floatx4*)&out[MU_OFF + bg * Ll + g * 4] = smv;
        *(floatx4*)&out[LV_OFF + bg * Ll + g * 4] = svv;
        floatx4 ev = *(const floatx4*)&eps[bg * Ll + g * 4];
        #pragma unroll
        for (int ii = 0; ii < 4; ii++)
            ctx_s[b * CXP + g * 4 + ii] = (__bf16)(sm[ii] + ev[ii] * __expf(0.5f * sv[ii]));
        __syncthreads();                                  // z/ctx complete

        // h0 = ctx·W_fch^T + b_fch  -> hbuf[0] (overwrites h_enc; reads done)
        #pragma unroll
        for (int i4 = 0; i4 < 4; i4++) {
            bf16x4 hq;
            #pragma unroll
            for (int r2 = 0; r2 < 4; r2++) {
                int j = g * 16 + i4 * 4 + r2;
                float s = b_fch[j];
                const float* wf = W_fch + j * 40;
                #pragma unroll 8
                for (int k = 0; k < 40; k++) s += (float)ctx_s[b * CXP + k] * wf[k];
                hq[r2] = (__bf16)s;
            }
            *(bf16x4*)&hbuf[0][b * HP + g * 16 + i4 * 4] = hq;
        }
        // dec_tab overwrites enc_tab
        for (int i = tid; i < Vv * G3; i += 512)
            tab_s[(i / G3) * TABP + (i % G3)] = (__bf16)tabs[Vv * G3 + i];
        __syncthreads();
    }

    // ---- decoder W_hh A-frags + b_hh_d n-bias ----
    #pragma unroll
    for (int role = 0; role < 3; role++)
        #pragma unroll
        for (int kb = 0; kb < 4; kb++) {
            const float* p = W_hh_d + (role * Hh + w * 16 + li) * Hh + kb * 32 + q * 8;
            bf16x8 f;
            #pragma unroll
            for (int jj = 0; jj < 8; jj++) f[jj] = (__bf16)p[jj];
            aW[role][kb] = f;
        }
    #pragma unroll
    for (int r = 0; r < 4; r++) bhn[r] = b_hh_d[2 * Hh + w * 16 + q * 4 + r];

    // ---- t-invariant base = ctx·W_ihd_ctx (biases already in tab) ----
    floatx4 base[3][4];
    #pragma unroll
    for (int role = 0; role < 3; role++)
        #pragma unroll
        for (int nt = 0; nt < 4; nt++) base[role][nt] = zf;
    #pragma unroll
    for (int kb2 = 0; kb2 < 2; kb2++) {
        bf16x8 aC[3];
        #pragma unroll
        for (int role = 0; role < 3; role++) {
            int row = role * Hh + w * 16 + li;
            bf16x8 f;
            #pragma unroll
            for (int jj = 0; jj < 8; jj++) {
                int k = kb2 * 32 + q * 8 + jj;
                f[jj] = (k < 40) ? (__bf16)W_ih_d[row * 104 + Ee + k] : (__bf16)0.f;
            }
            aC[role] = f;
        }
        #pragma unroll
        for (int nt = 0; nt < 4; nt++) {
            bf16x8 cf = *(const bf16x8*)&ctx_s[(nt * 16 + li) * CXP + kb2 * 32 + q * 8];
            #pragma unroll
            for (int role = 0; role < 3; role++)
                base[role][nt] = __builtin_amdgcn_mfma_f32_16x16x32_bf16(aC[role], cf, base[role][nt], 0, 0, 0);
        }
    }

    // ---- W_out frags: wave w -> (mt_o = w&1, nt_o = w>>1) ----
    const int mt_o = w & 1, nt_o = w >> 1;
    bf16x8 aO[4];
    #pragma unroll
    for (int kb = 0; kb < 4; kb++) {
        int row = mt_o * 16 + li;
        bf16x8 f;
        #pragma unroll
        for (int jj = 0; jj < 8; jj++)
            f[jj] = (row < Vv) ? (__bf16)W_out[row * Hh + kb * 32 + q * 8 + jj] : (__bf16)0.f;
        aO[kb] = f;
    }
    float bo[4];
    #pragma unroll
    for (int r = 0; r < 4; r++) {
        int v = mt_o * 16 + q * 4 + r;
        bo[r] = (v < Vv) ? b_out[v] : 0.f;
    }

    // h0 -> hreg (C-layout)
    #pragma unroll
    for (int nt = 0; nt < 4; nt++)
        #pragma unroll
        for (int r = 0; r < 4; r++)
            hreg[nt][r] = (float)hbuf[0][(nt * 16 + li) * HP + w * 16 + q * 4 + r];

    // ---- one decoder step; emits recon[t-1] from hf (fused) ----
    auto dec_step = [&](int t, const __bf16* hr, __bf16* hw) {
        bf16x8 hf[4][4];
        #pragma unroll
        for (int nt = 0; nt < 4; nt++)
            #pragma unroll
            for (int kb = 0; kb < 4; kb++)
                hf[nt][kb] = *(const bf16x8*)&hr[(nt * 16 + li) * HP + kb * 32 + q * 8];
        bf16x4 tR[4], tZ[4], tN[4];
        #pragma unroll
        for (int nt = 0; nt < 4; nt++) {
            int tok = x_s[(nt * 16 + li) * Tt + t];
            const __bf16* tp = &tab_s[tok * TABP + w * 16 + q * 4];
            tR[nt] = *(const bf16x4*)(tp);
            tZ[nt] = *(const bf16x4*)(tp + Hh);
            tN[nt] = *(const bf16x4*)(tp + 2 * Hh);
        }
        if (t > 0) {                                      // recon[t-1] from hf
            floatx4 po = zf;
            #pragma unroll
            for (int kb = 0; kb < 4; kb++)
                po = __builtin_amdgcn_mfma_f32_16x16x32_bf16(aO[kb], hf[nt_o][kb], po, 0, 0, 0);
            #pragma unroll
            for (int r = 0; r < 4; r++) {
                int v = mt_o * 16 + q * 4 + r;
                if (v < Vv)
                    out[((size_t)(b0 + nt_o * 16 + li) * 13 + (t - 1)) * Vv + v] = po[r] + bo[r];
            }
        }
        floatx4 acc[3][4];
        #pragma unroll
        for (int nt = 0; nt < 4; nt++) {
            acc[0][nt] = __builtin_amdgcn_mfma_f32_16x16x32_bf16(aW[0][0], hf[nt][0], base[0][nt], 0, 0, 0);
            acc[1][nt] = __builtin_amdgcn_mfma_f32_16x16x32_bf16(aW[1][0], hf[nt][0], base[1][nt], 0, 0, 0);
            acc[2][nt] = __builtin_amdgcn_mfma_f32_16x16x32_bf16(aW[2][0], hf[nt][0], zf, 0, 0, 0);
        }
        #pragma unroll
        for (int kb = 1; kb < 4; kb++)
            #pragma unroll
            for (int role = 0; role < 3; role++)
                #pragma unroll
                for (int nt = 0; nt < 4; nt++)
                    acc[role][nt] = __builtin_amdgcn_mfma_f32_16x16x32_bf16(
                        aW[role][kb], hf[nt][kb], acc[role][nt], 0, 0, 0);
        #pragma unroll
        for (int nt = 0; nt < 4; nt++) {
            bf16x4 hv;
            #pragma unroll
            for (int r = 0; r < 4; r++) {
                float rr = sigm(acc[0][nt][r] + (float)tR[nt][r]);
                float zz = sigm(acc[1][nt][r] + (float)tZ[nt][r]);
                float nn = tanhg(base[2][nt][r] + (float)tN[nt][r] + rr * (acc[2][nt][r] + bhn[r]));
                float h  = (1.f - zz) * nn + zz * hreg[nt][r];
                hreg[nt][r] = h;
                hv[r] = (__bf16)h;
            }
            *(bf16x4*)&hw[(nt * 16 + li) * HP + w * 16 + q * 4] = hv;
        }
        __syncthreads();
    };

    // ================= decoder: 13 steps =================
    for (int t2 = 0; t2 < 12; t2 += 2) {
        dec_step(t2,     hbuf[0], hbuf[1]);
        dec_step(t2 + 1, hbuf[1], hbuf[0]);
    }
    dec_step(12, hbuf[0], hbuf[1]);

    // final recon[12] from hbuf[1]
    {
        floatx4 po = zf;
        #pragma unroll
        for (int kb = 0; kb < 4; kb++) {
            bf16x8 hf = *(const bf16x8*)&hbuf[1][(nt_o * 16 + li) * HP + kb * 32 + q * 8];
            po = __builtin_amdgcn_mfma_f32_16x16x32_bf16(aO[kb], hf, po, 0, 0, 0);
        }
        #pragma unroll
        for (int r = 0; r < 4; r++) {
            int v = mt_o * 16 + q * 4 + r;
            if (v < Vv)
                out[((size_t)(b0 + nt_o * 16 + li) * 13 + 12) * Vv + v] = po[r] + bo[r];
        }
    }
}

extern "C" void kernel_launch(void* const* d_in, const int* in_sizes, int n_in,
                              void* d_out, int out_size, void* d_ws, size_t ws_size,
                              hipStream_t stream)
{
    const int*   x       = (const int*)d_in[0];
    const float* c       = (const float*)d_in[1];
    const float* eps     = (const float*)d_in[2];
    const float* emb_enc = (const float*)d_in[3];
    const float* W_ih_e  = (const float*)d_in[4];
    const float* W_hh_e  = (const float*)d_in[5];
    const float* b_ih_e  = (const float*)d_in[6];
    const float* b_hh_e  = (const float*)d_in[7];
    const float* W_mu    = (const float*)d_in[8];
    const float* b_mu    = (const float*)d_in[9];
    const float* W_lv    = (const float*)d_in[10];
    const float* b_lv    = (const float*)d_in[11];
    const float* emb_dec = (const float*)d_in[12];
    const float* W_fch   = (const float*)d_in[13];
    const float* b_fch   = (const float*)d_in[14];
    const float* W_ih_d  = (const float*)d_in[15];
    const float* W_hh_d  = (const float*)d_in[16];
    const float* b_ih_d  = (const float*)d_in[17];
    const float* b_hh_d  = (const float*)d_in[18];
    const float* W_out   = (const float*)d_in[19];
    const float* b_out   = (const float*)d_in[20];

    float* ws = (float*)d_ws;
    const int Btot = in_sizes[0] / Tt;

    cvae_tables<<<75, 256, 0, stream>>>(emb_enc, W_ih_e, b_ih_e, b_hh_e,
                                        emb_dec, W_ih_d, b_ih_d, b_hh_d, ws);

    cvae_mfma<<<Btot / 64, 512, 0, stream>>>(
        x, c, eps, W_hh_e, b_hh_e, W_mu, b_mu, W_lv, b_lv,
        W_fch, b_fch, W_ih_d, W_hh_d, b_hh_d, W_out, b_out,
        ws, (float*)d_out, Btot);
}

// Round 5
// 861.529 us; speedup vs baseline: 1.0625x; 1.0625x over previous
//
#include <hip/hip_runtime.h>

typedef __bf16 bf16x8 __attribute__((ext_vector_type(8)));
typedef __bf16 bf16x4 __attribute__((ext_vector_type(4)));
typedef float  floatx4 __attribute__((ext_vector_type(4)));

#define Vv 25
#define Tt 14
#define Ee 64
#define Hh 128
#define Ll 32
#define Ccc 8
#define G3 384
#define TABP 396   // token-table row stride (bf16): word-stride 198 = 6 mod 32
#define HP   136   // h row stride (bf16): 128+8, rows 16B-aligned
#define CXP  72    // ctx row stride (bf16): 64+8

// ---------------------------------------------------------------------------
// Kernel A: token -> input-projection tables (f32, in ws), biases folded:
//   enc_tab[v][j] = emb_enc[v]·W_ih_e[j] + b_ih_e[j] + (j<256 ? b_hh_e[j] : 0)
//   dec_tab[v][j] = emb_dec[v]·W_ih_d[j][:64] + b_ih_d[j] + (j<256 ? b_hh_d[j] : 0)
// ---------------------------------------------------------------------------
extern "C" __global__ void __launch_bounds__(256)
cvae_tables(const float* __restrict__ emb_enc, const float* __restrict__ W_ih_e,
            const float* __restrict__ b_ih_e, const float* __restrict__ b_hh_e,
            const float* __restrict__ emb_dec, const float* __restrict__ W_ih_d,
            const float* __restrict__ b_ih_d, const float* __restrict__ b_hh_d,
            float* __restrict__ ws)
{
    int id = blockIdx.x * 256 + threadIdx.x;
    if (id >= 2 * Vv * G3) return;
    int half = id / (Vv * G3);
    int r = id % (Vv * G3);
    int v = r / G3, j = r % G3;
    if (half == 0) {
        float acc = b_ih_e[j] + ((j < 2 * Hh) ? b_hh_e[j] : 0.0f);
        const float* e = emb_enc + v * Ee;
        const float* w = W_ih_e + j * Ee;
        #pragma unroll 4
        for (int k = 0; k < Ee; k++) acc += e[k] * w[k];
        ws[v * G3 + j] = acc;
    } else {
        float acc = b_ih_d[j] + ((j < 2 * Hh) ? b_hh_d[j] : 0.0f);
        const float* e = emb_dec + v * Ee;
        const float* w = W_ih_d + j * 104;
        #pragma unroll 4
        for (int k = 0; k < Ee; k++) acc += e[k] * w[k];
        ws[Vv * G3 + v * G3 + j] = acc;
    }
}

__device__ __forceinline__ float rcp_f(float x) { return __builtin_amdgcn_rcpf(x); }
__device__ __forceinline__ float sigm(float x)  { return rcp_f(1.0f + __expf(-x)); }
__device__ __forceinline__ float tanhg(float x) { return 1.0f - 2.0f * rcp_f(1.0f + __expf(2.0f * x)); }

// ---------------------------------------------------------------------------
// Fused CVAE forward. 512 thr = 8 waves, 64 batch rows/block.
// gh^T = W·h^T: A-frag = stationary W rows in regs; B-frag = h in LDS bf16;
// C tile: col=lane&15=batch, row=q*4+reg=j-local. Wave w owns j in [16w,16w+16).
// Double-buffered h: ONE barrier per GRU step. Vocab proj for step t-1 fused
// into iter t (reuses hf fragments). LDS = 64728 B.
// __launch_bounds__(512,2): 2 waves/SIMD -> 256-unified-reg cap. DO NOT drop
// the ",2" — without it the compiler budgets for 1024-thr blocks (128-reg cap)
// and spills ~2 GB/launch to scratch (measured round 4).
// ---------------------------------------------------------------------------
extern "C" __global__ void __launch_bounds__(512, 2)
cvae_mfma(const int* __restrict__ x, const float* __restrict__ cin,
          const float* __restrict__ eps,
          const float* __restrict__ W_hh_e, const float* __restrict__ b_hh_e,
          const float* __restrict__ W_mu, const float* __restrict__ b_mu,
          const float* __restrict__ W_lv, const float* __restrict__ b_lv,
          const float* __restrict__ W_fch, const float* __restrict__ b_fch,
          const float* __restrict__ W_ih_d, const float* __restrict__ W_hh_d,
          const float* __restrict__ b_hh_d,
          const float* __restrict__ W_out, const float* __restrict__ b_out,
          const float* __restrict__ tabs, float* __restrict__ out, int Btot)
{
    __shared__ __attribute__((aligned(16))) __bf16 hbuf[2][64 * HP];  // 34816 B
    __shared__ __attribute__((aligned(16))) __bf16 tab_s[Vv * TABP];  // 19800 B
    __shared__ __attribute__((aligned(16))) __bf16 ctx_s[64 * CXP];   //  9216 B
    __shared__ unsigned char x_s[64 * Tt];                            //   896 B

    const int tid  = threadIdx.x;
    const int w    = tid >> 6;
    const int lane = tid & 63;
    const int li   = lane & 15;
    const int q    = lane >> 4;
    const int b0   = blockIdx.x * 64;
    const size_t MU_OFF = (size_t)Btot * 13 * Vv;
    const size_t LV_OFF = MU_OFF + (size_t)Btot * Ll;
    const floatx4 zf = {0.f, 0.f, 0.f, 0.f};

    // ---- stage tokens + enc_tab (bf16), zero h buf0, stage c into ctx ----
    for (int i = tid; i < 64 * Tt; i += 512) x_s[i] = (unsigned char)x[(size_t)b0 * Tt + i];
    for (int i = tid; i < Vv * G3; i += 512)
        tab_s[(i / G3) * TABP + (i % G3)] = (__bf16)tabs[i];
    for (int i = tid; i < 64 * HP; i += 512) hbuf[0][i] = (__bf16)0.f;
    {   // c: tid = bb*8+cc covers 64x8 exactly
        int bb = tid >> 3, cc = tid & 7;
        ctx_s[bb * CXP + Ll + cc] = (__bf16)cin[((size_t)b0 + bb) * Ccc + cc];
    }
    {   // zero ctx cols 40..71 (K-padding for base MFMA)
        int bb = tid >> 3, k = tid & 7;
        #pragma unroll
        for (int kk = 0; kk < 4; kk++) ctx_s[bb * CXP + 40 + k * 4 + kk] = (__bf16)0.f;
    }

    // ---- encoder W_hh A-frags (stationary) + b_hh_n ----
    bf16x8 aW[3][4];
    #pragma unroll
    for (int role = 0; role < 3; role++)
        #pragma unroll
        for (int kb = 0; kb < 4; kb++) {
            const float* p = W_hh_e + (role * Hh + w * 16 + li) * Hh + kb * 32 + q * 8;
            bf16x8 f;
            #pragma unroll
            for (int jj = 0; jj < 8; jj++) f[jj] = (__bf16)p[jj];
            aW[role][kb] = f;
        }
    float bhn[4];
    #pragma unroll
    for (int r = 0; r < 4; r++) bhn[r] = b_hh_e[2 * Hh + w * 16 + q * 4 + r];

    float hreg[4][4];
    #pragma unroll
    for (int nt = 0; nt < 4; nt++)
        #pragma unroll
        for (int r = 0; r < 4; r++) hreg[nt][r] = 0.f;

    __syncthreads();

    // ---- one encoder GRU step: read hr, write hw, one barrier ----
    auto enc_step = [&](int t, const __bf16* hr, __bf16* hw) {
        bf16x8 hf[4][4];
        #pragma unroll
        for (int nt = 0; nt < 4; nt++)
            #pragma unroll
            for (int kb = 0; kb < 4; kb++)
                hf[nt][kb] = *(const bf16x8*)&hr[(nt * 16 + li) * HP + kb * 32 + q * 8];
        floatx4 acc[3][4];
        #pragma unroll
        for (int nt = 0; nt < 4; nt++)
            #pragma unroll
            for (int role = 0; role < 3; role++)
                acc[role][nt] = __builtin_amdgcn_mfma_f32_16x16x32_bf16(aW[role][0], hf[nt][0], zf, 0, 0, 0);
        #pragma unroll
        for (int kb = 1; kb < 4; kb++)
            #pragma unroll
            for (int role = 0; role < 3; role++)
                #pragma unroll
                for (int nt = 0; nt < 4; nt++)
                    acc[role][nt] = __builtin_amdgcn_mfma_f32_16x16x32_bf16(
                        aW[role][kb], hf[nt][kb], acc[role][nt], 0, 0, 0);
        // token-table reads AFTER the MFMA chain: hf dies as tabs load
        bf16x4 tR[4], tZ[4], tN[4];
        #pragma unroll
        for (int nt = 0; nt < 4; nt++) {
            int tok = x_s[(nt * 16 + li) * Tt + t];
            const __bf16* tp = &tab_s[tok * TABP + w * 16 + q * 4];
            tR[nt] = *(const bf16x4*)(tp);
            tZ[nt] = *(const bf16x4*)(tp + Hh);
            tN[nt] = *(const bf16x4*)(tp + 2 * Hh);
        }
        #pragma unroll
        for (int nt = 0; nt < 4; nt++) {
            bf16x4 hv;
            #pragma unroll
            for (int r = 0; r < 4; r++) {
                float rr = sigm(acc[0][nt][r] + (float)tR[nt][r]);
                float zz = sigm(acc[1][nt][r] + (float)tZ[nt][r]);
                float nn = tanhg((float)tN[nt][r] + rr * (acc[2][nt][r] + bhn[r]));
                float h  = nn + zz * (hreg[nt][r] - nn);
                hreg[nt][r] = h;
                hv[r] = (__bf16)h;
            }
            *(bf16x4*)&hw[(nt * 16 + li) * HP + w * 16 + q * 4] = hv;
        }
        __syncthreads();
    };

    // ================= encoder: 14 steps (h_enc lands in hbuf[0]) ==========
    for (int t2 = 0; t2 < Tt; t2 += 2) {
        enc_step(t2,     hbuf[0], hbuf[1]);
        enc_step(t2 + 1, hbuf[1], hbuf[0]);
    }

    // ================= latent: mu / logvar / z =================
    {
        int b = tid & 63, g = w;
        size_t bg = (size_t)b0 + b;
        float cv[8];
        #pragma unroll
        for (int cc = 0; cc < 8; cc++) cv[cc] = cin[bg * Ccc + cc];

        float sm[4], sv[4];
        #pragma unroll
        for (int ii = 0; ii < 4; ii++) { sm[ii] = b_mu[g * 4 + ii]; sv[ii] = b_lv[g * 4 + ii]; }
        const __bf16* hp = &hbuf[0][b * HP];
        #pragma unroll 4
        for (int kb = 0; kb < 16; kb++) {
            bf16x8 h8 = *(const bf16x8*)&hp[kb * 8];
            #pragma unroll
            for (int jj = 0; jj < 8; jj++) {
                float hv = (float)h8[jj];
                int k = kb * 8 + jj;
                #pragma unroll
                for (int ii = 0; ii < 4; ii++) {
                    sm[ii] += hv * W_mu[(g * 4 + ii) * 136 + k];
                    sv[ii] += hv * W_lv[(g * 4 + ii) * 136 + k];
                }
            }
        }
        #pragma unroll
        for (int cc = 0; cc < 8; cc++)
            #pragma unroll
            for (int ii = 0; ii < 4; ii++) {
                sm[ii] += cv[cc] * W_mu[(g * 4 + ii) * 136 + Hh + cc];
                sv[ii] += cv[cc] * W_lv[(g * 4 + ii) * 136 + Hh + cc];
            }
        floatx4 smv, svv;
        #pragma unroll
        for (int ii = 0; ii < 4; ii++) { smv[ii] = sm[ii]; svv[ii] = sv[ii]; }
        *(floatx4*)&out[MU_OFF + bg * Ll + g * 4] = smv;
        *(floatx4*)&out[LV_OFF + bg * Ll + g * 4] = svv;
        floatx4 ev = *(const floatx4*)&eps[bg * Ll + g * 4];
        #pragma unroll
        for (int ii = 0; ii < 4; ii++)
            ctx_s[b * CXP + g * 4 + ii] = (__bf16)(sm[ii] + ev[ii] * __expf(0.5f * sv[ii]));
        __syncthreads();                                  // z/ctx complete

        // h0 = ctx·W_fch^T + b_fch  -> hbuf[0] (overwrites h_enc; reads done)
        #pragma unroll
        for (int i4 = 0; i4 < 4; i4++) {
            bf16x4 hq;
            #pragma unroll
            for (int r2 = 0; r2 < 4; r2++) {
                int j = g * 16 + i4 * 4 + r2;
                float s = b_fch[j];
                const float* wf = W_fch + j * 40;
                #pragma unroll 8
                for (int k = 0; k < 40; k++) s += (float)ctx_s[b * CXP + k] * wf[k];
                hq[r2] = (__bf16)s;
            }
            *(bf16x4*)&hbuf[0][b * HP + g * 16 + i4 * 4] = hq;
        }
        // dec_tab overwrites enc_tab
        for (int i = tid; i < Vv * G3; i += 512)
            tab_s[(i / G3) * TABP + (i % G3)] = (__bf16)tabs[Vv * G3 + i];
        __syncthreads();
    }

    // ---- decoder W_hh A-frags + b_hh_d n-bias ----
    #pragma unroll
    for (int role = 0; role < 3; role++)
        #pragma unroll
        for (int kb = 0; kb < 4; kb++) {
            const float* p = W_hh_d + (role * Hh + w * 16 + li) * Hh + kb * 32 + q * 8;
            bf16x8 f;
            #pragma unroll
            for (int jj = 0; jj < 8; jj++) f[jj] = (__bf16)p[jj];
            aW[role][kb] = f;
        }
    #pragma unroll
    for (int r = 0; r < 4; r++) bhn[r] = b_hh_d[2 * Hh + w * 16 + q * 4 + r];

    // ---- t-invariant base = ctx·W_ihd_ctx (biases already in tab) ----
    floatx4 base[3][4];
    #pragma unroll
    for (int role = 0; role < 3; role++)
        #pragma unroll
        for (int nt = 0; nt < 4; nt++) base[role][nt] = zf;
    #pragma unroll
    for (int kb2 = 0; kb2 < 2; kb2++) {
        bf16x8 aC[3];
        #pragma unroll
        for (int role = 0; role < 3; role++) {
            int row = role * Hh + w * 16 + li;
            bf16x8 f;
            #pragma unroll
            for (int jj = 0; jj < 8; jj++) {
                int k = kb2 * 32 + q * 8 + jj;
                f[jj] = (k < 40) ? (__bf16)W_ih_d[row * 104 + Ee + k] : (__bf16)0.f;
            }
            aC[role] = f;
        }
        #pragma unroll
        for (int nt = 0; nt < 4; nt++) {
            bf16x8 cf = *(const bf16x8*)&ctx_s[(nt * 16 + li) * CXP + kb2 * 32 + q * 8];
            #pragma unroll
            for (int role = 0; role < 3; role++)
                base[role][nt] = __builtin_amdgcn_mfma_f32_16x16x32_bf16(aC[role], cf, base[role][nt], 0, 0, 0);
        }
    }

    // ---- W_out frags: wave w -> (mt_o = w&1, nt_o = w>>1) ----
    const int mt_o = w & 1, nt_o = w >> 1;
    bf16x8 aO[4];
    #pragma unroll
    for (int kb = 0; kb < 4; kb++) {
        int row = mt_o * 16 + li;
        bf16x8 f;
        #pragma unroll
        for (int jj = 0; jj < 8; jj++)
            f[jj] = (row < Vv) ? (__bf16)W_out[row * Hh + kb * 32 + q * 8 + jj] : (__bf16)0.f;
        aO[kb] = f;
    }
    float bo[4];
    #pragma unroll
    for (int r = 0; r < 4; r++) {
        int v = mt_o * 16 + q * 4 + r;
        bo[r] = (v < Vv) ? b_out[v] : 0.f;
    }

    // h0 -> hreg (C-layout)
    #pragma unroll
    for (int nt = 0; nt < 4; nt++)
        #pragma unroll
        for (int r = 0; r < 4; r++)
            hreg[nt][r] = (float)hbuf[0][(nt * 16 + li) * HP + w * 16 + q * 4 + r];

    // ---- one decoder step; emits recon[t-1] from hf (fused) ----
    auto dec_step = [&](int t, const __bf16* hr, __bf16* hw) {
        bf16x8 hf[4][4];
        #pragma unroll
        for (int nt = 0; nt < 4; nt++)
            #pragma unroll
            for (int kb = 0; kb < 4; kb++)
                hf[nt][kb] = *(const bf16x8*)&hr[(nt * 16 + li) * HP + kb * 32 + q * 8];
        if (t > 0) {                                      // recon[t-1] from hf
            floatx4 po = zf;
            #pragma unroll
            for (int kb = 0; kb < 4; kb++)
                po = __builtin_amdgcn_mfma_f32_16x16x32_bf16(aO[kb], hf[nt_o][kb], po, 0, 0, 0);
            #pragma unroll
            for (int r = 0; r < 4; r++) {
                int v = mt_o * 16 + q * 4 + r;
                if (v < Vv)
                    out[((size_t)(b0 + nt_o * 16 + li) * 13 + (t - 1)) * Vv + v] = po[r] + bo[r];
            }
        }
        floatx4 acc[3][4];
        #pragma unroll
        for (int nt = 0; nt < 4; nt++) {
            acc[0][nt] = __builtin_amdgcn_mfma_f32_16x16x32_bf16(aW[0][0], hf[nt][0], base[0][nt], 0, 0, 0);
            acc[1][nt] = __builtin_amdgcn_mfma_f32_16x16x32_bf16(aW[1][0], hf[nt][0], base[1][nt], 0, 0, 0);
            acc[2][nt] = __builtin_amdgcn_mfma_f32_16x16x32_bf16(aW[2][0], hf[nt][0], zf, 0, 0, 0);
        }
        #pragma unroll
        for (int kb = 1; kb < 4; kb++)
            #pragma unroll
            for (int role = 0; role < 3; role++)
                #pragma unroll
                for (int nt = 0; nt < 4; nt++)
                    acc[role][nt] = __builtin_amdgcn_mfma_f32_16x16x32_bf16(
                        aW[role][kb], hf[nt][kb], acc[role][nt], 0, 0, 0);
        // token-table reads AFTER the MFMA chain
        bf16x4 tR[4], tZ[4], tN[4];
        #pragma unroll
        for (int nt = 0; nt < 4; nt++) {
            int tok = x_s[(nt * 16 + li) * Tt + t];       // dec_in = x[:, :-1]
            const __bf16* tp = &tab_s[tok * TABP + w * 16 + q * 4];
            tR[nt] = *(const bf16x4*)(tp);
            tZ[nt] = *(const bf16x4*)(tp + Hh);
            tN[nt] = *(const bf16x4*)(tp + 2 * Hh);
        }
        #pragma unroll
        for (int nt = 0; nt < 4; nt++) {
            bf16x4 hv;
            #pragma unroll
            for (int r = 0; r < 4; r++) {
                float rr = sigm(acc[0][nt][r] + (float)tR[nt][r]);
                float zz = sigm(acc[1][nt][r] + (float)tZ[nt][r]);
                float nn = tanhg(base[2][nt][r] + (float)tN[nt][r] + rr * (acc[2][nt][r] + bhn[r]));
                float h  = nn + zz * (hreg[nt][r] - nn);
                hreg[nt][r] = h;
                hv[r] = (__bf16)h;
            }
            *(bf16x4*)&hw[(nt * 16 + li) * HP + w * 16 + q * 4] = hv;
        }
        __syncthreads();
    };

    // ================= decoder: 13 steps =================
    for (int t2 = 0; t2 < 12; t2 += 2) {
        dec_step(t2,     hbuf[0], hbuf[1]);
        dec_step(t2 + 1, hbuf[1], hbuf[0]);
    }
    dec_step(12, hbuf[0], hbuf[1]);

    // final recon[12] from hbuf[1]
    {
        floatx4 po = zf;
        #pragma unroll
        for (int kb = 0; kb < 4; kb++) {
            bf16x8 hf = *(const bf16x8*)&hbuf[1][(nt_o * 16 + li) * HP + kb * 32 + q * 8];
            po = __builtin_amdgcn_mfma_f32_16x16x32_bf16(aO[kb], hf, po, 0, 0, 0);
        }
        #pragma unroll
        for (int r = 0; r < 4; r++) {
            int v = mt_o * 16 + q * 4 + r;
            if (v < Vv)
                out[((size_t)(b0 + nt_o * 16 + li) * 13 + 12) * Vv + v] = po[r] + bo[r];
        }
    }
}

extern "C" void kernel_launch(void* const* d_in, const int* in_sizes, int n_in,
                              void* d_out, int out_size, void* d_ws, size_t ws_size,
                              hipStream_t stream)
{
    const int*   x       = (const int*)d_in[0];
    const float* c       = (const float*)d_in[1];
    const float* eps     = (const float*)d_in[2];
    const float* emb_enc = (const float*)d_in[3];
    const float* W_ih_e  = (const float*)d_in[4];
    const float* W_hh_e  = (const float*)d_in[5];
    const float* b_ih_e  = (const float*)d_in[6];
    const float* b_hh_e  = (const float*)d_in[7];
    const float* W_mu    = (const float*)d_in[8];
    const float* b_mu    = (const float*)d_in[9];
    const float* W_lv    = (const float*)d_in[10];
    const float* b_lv    = (const float*)d_in[11];
    const float* emb_dec = (const float*)d_in[12];
    const float* W_fch   = (const float*)d_in[13];
    const float* b_fch   = (const float*)d_in[14];
    const float* W_ih_d  = (const float*)d_in[15];
    const float* W_hh_d  = (const float*)d_in[16];
    const float* b_ih_d  = (const float*)d_in[17];
    const float* b_hh_d  = (const float*)d_in[18];
    const float* W_out   = (const float*)d_in[19];
    const float* b_out   = (const float*)d_in[20];

    float* ws = (float*)d_ws;
    const int Btot = in_sizes[0] / Tt;

    cvae_tables<<<75, 256, 0, stream>>>(emb_enc, W_ih_e, b_ih_e, b_hh_e,
                                        emb_dec, W_ih_d, b_ih_d, b_hh_d, ws);

    cvae_mfma<<<Btot / 64, 512, 0, stream>>>(
        x, c, eps, W_hh_e, b_hh_e, W_mu, b_mu, W_lv, b_lv,
        W_fch, b_fch, W_ih_d, W_hh_d, b_hh_d, W_out, b_out,
        ws, (float*)d_out, Btot);
}